// Round 12
// baseline (1303.913 us; speedup 1.0000x reference)
//
#include <hip/hip_runtime.h>

#define EPS_ 1e-5f
#define SCALE_ 0.03125f   // DIM^-0.5 = 1/32

typedef __attribute__((ext_vector_type(8))) short short8;
typedef __attribute__((ext_vector_type(4))) float f32x4;
typedef unsigned short u16;

__device__ __forceinline__ float bf2f(u16 s) {
  return __uint_as_float(((unsigned int)s) << 16);
}
__device__ __forceinline__ u16 f2bf(float f) {
  unsigned int u = __float_as_uint(f);
  unsigned int r = 0x7FFFu + ((u >> 16) & 1u);
  return (u16)((u + r) >> 16);
}

// async global->LDS, 16B per lane; LDS dest must be linear in lane order
__device__ __forceinline__ void gload16(const void* g, void* l) {
  __builtin_amdgcn_global_load_lds(
      (const __attribute__((address_space(1))) unsigned int*)g,
      (__attribute__((address_space(3))) unsigned int*)l, 16, 0, 0);
}

// ---------- LN stats stage 1: partial sums per (c-chunk, row) ----------
__global__ __launch_bounds__(256) void ln_part(const float* __restrict__ x,
                                               float* __restrict__ ps,
                                               float* __restrict__ ps2) {
  int tl = threadIdx.x & 63;
  int cg = threadIdx.x >> 6;             // 0..3
  int lblk = blockIdx.x >> 3;
  int cchunk = blockIdx.x & 7;
  int row = lblk * 64 + tl;              // b*4096 + l
  int bb = row >> 12, l = row & 4095;
  const float* xp = x + (long)bb * 4194304L + l;
  int c0 = cchunk * 128 + cg;
  float s = 0.f, s2 = 0.f;
#pragma unroll
  for (int i = 0; i < 32; ++i) {
    float v = xp[(long)(c0 + i * 4) * 4096];
    s += v; s2 += v * v;
  }
  __shared__ float sh[2][4][64];
  sh[0][cg][tl] = s; sh[1][cg][tl] = s2;
  __syncthreads();
  if (threadIdx.x < 64) {
    float ts = sh[0][0][tl] + sh[0][1][tl] + sh[0][2][tl] + sh[0][3][tl];
    float t2 = sh[1][0][tl] + sh[1][1][tl] + sh[1][2][tl] + sh[1][3][tl];
    ps[cchunk * 32768 + row] = ts;
    ps2[cchunk * 32768 + row] = t2;
  }
}

// ---------- LN stats stage 2: reduce 8 chunks -> mean/rstd ----------
__global__ __launch_bounds__(256) void ln_red(const float* __restrict__ ps,
                                              const float* __restrict__ ps2,
                                              float* __restrict__ meanp,
                                              float* __restrict__ rstdp) {
  int row = blockIdx.x * 256 + threadIdx.x;
  float s = 0.f, s2 = 0.f;
#pragma unroll
  for (int k = 0; k < 8; ++k) {
    s += ps[k * 32768 + row];
    s2 += ps2[k * 32768 + row];
  }
  float mu = s * (1.0f / 1024.0f);
  float var = s2 * (1.0f / 1024.0f) - mu * mu;
  meanp[row] = mu;
  rstdp[row] = rsqrtf(var + EPS_);
}

// ---------- xn[b][l][c] = bf16(LN(x[b][c][l])) via LDS tile transpose ----------
__global__ __launch_bounds__(256) void xn_make(const float* __restrict__ x,
                                               u16* __restrict__ xn,
                                               const float* __restrict__ meanp,
                                               const float* __restrict__ rstdp,
                                               const float* __restrict__ g,
                                               const float* __restrict__ beta) {
  __shared__ float tile[32][33];
  int b = blockIdx.z;
  int ct = blockIdx.y * 32;
  int lt = blockIdx.x * 32;
  int tx = threadIdx.x & 31, ty = threadIdx.x >> 5;
  const float* xp = x + (long)b * 4194304;
  int l = lt + tx;
  float mu = meanp[(b << 12) + l];
  float rs = rstdp[(b << 12) + l];
#pragma unroll
  for (int k = 0; k < 32; k += 8) {
    int c = ct + ty + k;
    float v = xp[(long)c * 4096 + l];
    tile[ty + k][tx] = (v - mu) * rs * g[c] + beta[c];
  }
  __syncthreads();
  u16* xq = xn + (long)b * 4194304;
#pragma unroll
  for (int k = 0; k < 32; k += 8) {
    int ll = lt + ty + k;
    xq[(long)ll * 1024 + ct + tx] = f2bf(tile[tx][ty + k]);
  }
}

// ---------- fp32 transpose (templates out): dst[z][c][r] = src[z][r][c] ----------
__global__ __launch_bounds__(256) void transpose_f32(const float* __restrict__ src,
                                                     float* __restrict__ dst,
                                                     int R, int Cc, long sSrc, long sDst) {
  __shared__ float tile[32][33];
  int z = blockIdx.z;
  int rt = blockIdx.y * 32, ct = blockIdx.x * 32;
  int tx = threadIdx.x & 31, ty = threadIdx.x >> 5;
  const float* s = src + (long)z * sSrc;
  float* d = dst + (long)z * sDst;
#pragma unroll
  for (int k = 0; k < 32; k += 8) tile[ty + k][tx] = s[(long)(rt + ty + k) * Cc + ct + tx];
  __syncthreads();
#pragma unroll
  for (int k = 0; k < 32; k += 8) d[(long)(ct + ty + k) * R + rt + tx] = tile[tx][ty + k];
}

// ---------- transpose + cast fp32 [R,C] -> bf16 [C,R] ----------
__global__ __launch_bounds__(256) void tcast(const float* __restrict__ src,
                                             u16* __restrict__ dst, int R, int C) {
  __shared__ float tile[32][33];
  int rt = blockIdx.y * 32, ct = blockIdx.x * 32;
  int tx = threadIdx.x & 31, ty = threadIdx.x >> 5;
#pragma unroll
  for (int k = 0; k < 32; k += 8) tile[ty + k][tx] = src[(long)(rt + ty + k) * C + ct + tx];
  __syncthreads();
#pragma unroll
  for (int k = 0; k < 32; k += 8) dst[(long)(ct + ty + k) * R + rt + tx] = f2bf(tile[tx][ty + k]);
}

// ---------- elementwise cast fp32 -> bf16 ----------
__global__ __launch_bounds__(256) void castbf(const float* __restrict__ in,
                                              u16* __restrict__ out) {
  long i = (long)blockIdx.x * 256 + threadIdx.x;
  out[i] = f2bf(in[i]);
}

// ---------- MFMA NT GEMM: C[m][n] = sum_k A[m][k]*Bt[n][k], bf16 in, fp32 acc ----
// BM=128, BN=128 or 64 (template), BK=64, 256 thr (4 waves).
// 2-phase double-buffered staging + XOR-swizzled LDS (rule #21).
// E_PART: atomic-free split-K partial slabs (stride 2^21 floats).
enum { E_BF16 = 0, E_SCALEBF = 1, E_F32 = 2, E_PART = 3, E_RELU = 4, E_ADDB = 5 };

template <int EPI, int KSPLIT = 1, int BN = 128>
__global__ __launch_bounds__(256) void mgemm(
    const u16* __restrict__ A, const u16* __restrict__ Bt, void* __restrict__ Cv,
    int K, int lda, int ldb, int ldc, long sA, long sB, long sC,
    const float* __restrict__ bias, const float* __restrict__ colsum) {
  __shared__ u16 Als[2][128 * 64];
  __shared__ u16 Bls[2][BN * 64];
  constexpr int NJ = BN / 32;     // B-fragments per wave (4 or 2)
  constexpr int NBS = BN / 32;    // B staging chunks per thread (4 or 2)
  const int tid = threadIdx.x;
  const int zb = (KSPLIT == 1) ? blockIdx.z : blockIdx.z / KSPLIT;
  const int ks = (KSPLIT == 1) ? 0 : blockIdx.z % KSPLIT;
  const int bm = blockIdx.y * 128;
  const int bn = blockIdx.x * BN;
  A += (long)zb * sA;
  Bt += (long)zb * sB;
  const int kpart = K / KSPLIT;
  const int kbase = ks * kpart;
  const int lane = tid & 63;
  const int w = tid >> 6;
  const int wm = (w & 1) * 64;
  const int wn = (w >> 1) * (BN / 2);
  const int fr = lane & 15;
  const int fq = lane >> 4;
  const int frx = fr & 7;                 // read-side XOR key (row&7 == fr&7)
  f32x4 acc[4][NJ] = {};

  const int srow = tid >> 3;
  // source chunk pre-swizzle: LDS chunk (tid&7) <- global chunk (tid&7)^(row&7)
  const int sko = (((tid & 7) ^ (srow & 7)) << 3);
  const u16* Ag = A + (long)(bm + srow) * lda + kbase + sko;
  const u16* Bg = Bt + (long)(bn + srow) * ldb + kbase + sko;
  const long astep = 32L * lda;
  const long bstep = 32L * ldb;

#define STAGE_(bufI, kOff)                                                   \
  {                                                                          \
    _Pragma("unroll") for (int i_ = 0; i_ < 4; ++i_)                         \
      gload16(Ag + i_ * astep + (kOff), &Als[bufI][tid * 8 + i_ * 2048]);    \
    _Pragma("unroll") for (int i_ = 0; i_ < NBS; ++i_)                       \
      gload16(Bg + i_ * bstep + (kOff), &Bls[bufI][tid * 8 + i_ * 2048]);    \
  }

#define COMPUTE_(bufI)                                                       \
  {                                                                          \
    _Pragma("unroll") for (int kc = 0; kc < 2; ++kc) {                       \
      const int kx = ((kc * 4 + fq) ^ frx) << 3;                             \
      short8 af[4], bv[NJ];                                                  \
      _Pragma("unroll") for (int i = 0; i < 4; ++i)                          \
          af[i] = *(const short8*)&Als[bufI][(wm + i * 16 + fr) * 64 + kx];  \
      _Pragma("unroll") for (int j = 0; j < NJ; ++j)                         \
          bv[j] = *(const short8*)&Bls[bufI][(wn + j * 16 + fr) * 64 + kx];  \
      _Pragma("unroll") for (int i = 0; i < 4; ++i)                          \
          _Pragma("unroll") for (int j = 0; j < NJ; ++j)                     \
              acc[i][j] = __builtin_amdgcn_mfma_f32_16x16x32_bf16(           \
                  af[i], bv[j], acc[i][j], 0, 0, 0);                         \
    }                                                                        \
  }

  const int nsteps = kpart >> 6;   // even at all call sites (8/16)
  STAGE_(0, 0);
  __syncthreads();
  for (int s = 0; s < nsteps - 2; s += 2) {
    STAGE_(1, (s + 1) * 64);
    COMPUTE_(0);
    __syncthreads();
    STAGE_(0, (s + 2) * 64);
    COMPUTE_(1);
    __syncthreads();
  }
  STAGE_(1, (nsteps - 1) * 64);
  COMPUTE_(0);
  __syncthreads();
  COMPUTE_(1);
#undef STAGE_
#undef COMPUTE_

  // C/D frag mapping: col = lane&15, row = (lane>>4)*4 + r
#pragma unroll
  for (int i = 0; i < 4; ++i) {
#pragma unroll
    for (int j = 0; j < NJ; ++j) {
      int gc = bn + wn + j * 16 + fr;
#pragma unroll
      for (int r = 0; r < 4; ++r) {
        int gr = bm + wm + i * 16 + fq * 4 + r;
        float v = acc[i][j][r];
        if constexpr (EPI == E_BF16) {
          ((u16*)Cv + (long)zb * sC)[(long)gr * ldc + gc] = f2bf(v);
        } else if constexpr (EPI == E_SCALEBF) {
          ((u16*)Cv + (long)zb * sC)[(long)gr * ldc + gc] = f2bf(v * SCALE_);
        } else if constexpr (EPI == E_F32) {
          ((float*)Cv + (long)zb * sC)[(long)gr * ldc + gc] = v;
        } else if constexpr (EPI == E_PART) {
          // plain store of normalized partial into slab ks (stride 2^21 floats)
          float* C = (float*)Cv + ((long)ks << 21) + (long)zb * sC;
          C[(long)gr * ldc + gc] = v * (1.0f / colsum[zb * 256 + gr]);
        } else if constexpr (EPI == E_RELU) {
          float h = v + bias[gc];
          ((u16*)Cv + (long)zb * sC)[(long)gr * ldc + gc] = f2bf(h > 0.f ? h : 0.f);
        } else {  // E_ADDB (non-atomic, KSPLIT==1 only)
          float* C = (float*)Cv + (long)zb * sC;
          C[(long)gr * ldc + gc] += v + bias[gc];
        }
      }
    }
  }
}

// ---------- fused logits GEMM + softmax(n) + colsum ----------
// BM=256 (all n slots), BNF-wide l-tile (template), K=1024. 4 waves in M.
// Single-buffered (verified structure). BNF=32: grid 128x8=1024 blocks =
// 4 blocks/CU (was 2) -- TLP hides the single-buffer stage drain (m114).
// ~37 KB LDS. Per-output math identical to BNF=64 -> bit-identical result.
template <int BNF>
__global__ __launch_bounds__(256) void fls(const u16* __restrict__ qk,
                                           const u16* __restrict__ xn,
                                           u16* __restrict__ attnbf,
                                           float* __restrict__ colsum) {
  __shared__ u16 Als[256 * 64];    // 32 KB, qk rows (n)
  __shared__ u16 Bls[BNF * 64];    // xn rows (l)
  __shared__ float sred[4][BNF];
  __shared__ float ssum[4][BNF];
  constexpr int NJ = BNF / 16;     // l-fragments per lane-col group
  constexpr int NBS = BNF / 32;    // B staging gloads
  const int tid = threadIdx.x;
  const int z = blockIdx.z;
  const int l0 = blockIdx.x * BNF;
  const u16* A = qk + (long)z * 262144;     // [256][1024]
  const u16* B = xn + (long)z * 4194304;    // [4096][1024]
  const int lane = tid & 63;
  const int w = tid >> 6;
  const int wm = w * 64;
  const int fr = lane & 15, fq = lane >> 4;
  const int frx = fr & 7;
  f32x4 acc[4][NJ] = {};

  const int srow = tid >> 3;
  const int sko = (((tid & 7) ^ (srow & 7)) << 3);
  const u16* Ag = A + (long)srow * 1024 + sko;
  const u16* Bg = B + (long)(l0 + srow) * 1024 + sko;
  u16* Al = Als + tid * 8;
  u16* Bl = Bls + tid * 8;

  for (int k0 = 0; k0 < 1024; k0 += 64) {
#pragma unroll
    for (int i = 0; i < 8; ++i)
      gload16(Ag + (long)i * 32768 + k0, Al + i * 2048);
#pragma unroll
    for (int i = 0; i < NBS; ++i)
      gload16(Bg + (long)i * 32768 + k0, Bl + i * 2048);
    __syncthreads();
#pragma unroll
    for (int kc = 0; kc < 2; ++kc) {
      const int kx = ((kc * 4 + fq) ^ frx) << 3;
      short8 af[4], bf[NJ];
#pragma unroll
      for (int i = 0; i < 4; ++i)
        af[i] = *(const short8*)&Als[(wm + i * 16 + fr) * 64 + kx];
#pragma unroll
      for (int j = 0; j < NJ; ++j)
        bf[j] = *(const short8*)&Bls[(j * 16 + fr) * 64 + kx];
#pragma unroll
      for (int i = 0; i < 4; ++i)
#pragma unroll
        for (int j = 0; j < NJ; ++j)
          acc[i][j] = __builtin_amdgcn_mfma_f32_16x16x32_bf16(af[i], bf[j], acc[i][j], 0, 0, 0);
    }
    __syncthreads();
  }

  // ---- softmax over n (256) per l-col; lane holds rows (i,r) of cols (j,fr)
  float mj[NJ];
#pragma unroll
  for (int j = 0; j < NJ; ++j) {
    float m = acc[0][j][0];
#pragma unroll
    for (int i = 0; i < 4; ++i)
#pragma unroll
      for (int r = 0; r < 4; ++r) m = fmaxf(m, acc[i][j][r]);
    m = fmaxf(m, __shfl_xor(m, 16));
    m = fmaxf(m, __shfl_xor(m, 32));
    mj[j] = m;
  }
  if (fq == 0) {
#pragma unroll
    for (int j = 0; j < NJ; ++j) sred[w][j * 16 + fr] = mj[j];
  }
  __syncthreads();
  float M4[NJ];
#pragma unroll
  for (int j = 0; j < NJ; ++j) {
    int c = j * 16 + fr;
    M4[j] = fmaxf(fmaxf(sred[0][c], sred[1][c]), fmaxf(sred[2][c], sred[3][c]));
  }
  float pj[NJ];
#pragma unroll
  for (int j = 0; j < NJ; ++j) pj[j] = 0.f;
#pragma unroll
  for (int i = 0; i < 4; ++i)
#pragma unroll
    for (int j = 0; j < NJ; ++j)
#pragma unroll
      for (int r = 0; r < 4; ++r) {
        float e = __expf(acc[i][j][r] - M4[j]);
        acc[i][j][r] = e;
        pj[j] += e;
      }
#pragma unroll
  for (int j = 0; j < NJ; ++j) {
    pj[j] += __shfl_xor(pj[j], 16);
    pj[j] += __shfl_xor(pj[j], 32);
  }
  if (fq == 0) {
#pragma unroll
    for (int j = 0; j < NJ; ++j) ssum[w][j * 16 + fr] = pj[j];
  }
  __syncthreads();
  float inv[NJ];
#pragma unroll
  for (int j = 0; j < NJ; ++j) {
    int c = j * 16 + fr;
    inv[j] = 1.0f / (ssum[0][c] + ssum[1][c] + ssum[2][c] + ssum[3][c]);
  }
  // ---- write bf16 attn + colsum partials
  u16* outp = attnbf + (long)z * 1048576;
#pragma unroll
  for (int i = 0; i < 4; ++i) {
#pragma unroll
    for (int r = 0; r < 4; ++r) {
      int n = wm + i * 16 + fq * 4 + r;
      float cs = 0.f;
#pragma unroll
      for (int j = 0; j < NJ; ++j) {
        float a = acc[i][j][r] * inv[j] + 1e-8f;
        u16 ab = f2bf(a);
        outp[(long)n * 4096 + l0 + j * 16 + fr] = ab;
        cs += bf2f(ab);
      }
      cs += __shfl_xor(cs, 1);
      cs += __shfl_xor(cs, 2);
      cs += __shfl_xor(cs, 4);
      cs += __shfl_xor(cs, 8);
      if (fr == 0) atomicAdd(&colsum[z * 256 + n], cs);
    }
  }
}

// ---------- row LN over D=1024, fp32 in -> bf16 out ----------
// part != null: xv = in + sum of 4 partial slabs (stride 2^21), write back to
// tupd (the updated templates), then LN.  cz != null: zero colsum.
__global__ __launch_bounds__(256) void row_ln_bf(const float* in,
                                                 float* tupd,
                                                 u16* __restrict__ out,
                                                 const float* __restrict__ g,
                                                 const float* __restrict__ bvec,
                                                 const float* part,
                                                 float* __restrict__ cz) {
  if (cz && blockIdx.x < 8) cz[blockIdx.x * 256 + threadIdx.x] = 0.f;
  long base = (long)blockIdx.x * 1024;
  int c = threadIdx.x << 2;
  float4 xv = *(const float4*)&in[base + c];
  if (part) {
    const float* p = part + base + c;
    float4 a0 = *(const float4*)(p);
    float4 a1 = *(const float4*)(p + 2097152);
    float4 a2 = *(const float4*)(p + 4194304);
    float4 a3 = *(const float4*)(p + 6291456);
    xv.x += a0.x + a1.x + a2.x + a3.x;
    xv.y += a0.y + a1.y + a2.y + a3.y;
    xv.z += a0.z + a1.z + a2.z + a3.z;
    xv.w += a0.w + a1.w + a2.w + a3.w;
    *(float4*)&tupd[base + c] = xv;
  }
  float s = xv.x + xv.y + xv.z + xv.w;
  float s2 = xv.x * xv.x + xv.y * xv.y + xv.z * xv.z + xv.w * xv.w;
#pragma unroll
  for (int off = 32; off > 0; off >>= 1) {
    s += __shfl_down(s, off);
    s2 += __shfl_down(s2, off);
  }
  __shared__ float sh[8];
  if ((threadIdx.x & 63) == 0) {
    sh[threadIdx.x >> 6] = s;
    sh[4 + (threadIdx.x >> 6)] = s2;
  }
  __syncthreads();
  float ts = sh[0] + sh[1] + sh[2] + sh[3];
  float t2 = sh[4] + sh[5] + sh[6] + sh[7];
  float mu = ts * (1.0f / 1024.0f);
  float rs = rsqrtf(t2 * (1.0f / 1024.0f) - mu * mu + EPS_);
  ushort4 o;
  o.x = f2bf((xv.x - mu) * rs * g[c + 0] + bvec[c + 0]);
  o.y = f2bf((xv.y - mu) * rs * g[c + 1] + bvec[c + 1]);
  o.z = f2bf((xv.z - mu) * rs * g[c + 2] + bvec[c + 2]);
  o.w = f2bf((xv.w - mu) * rs * g[c + 3] + bvec[c + 3]);
  *(ushort4*)&out[base + c] = o;
}

// ---------- broadcast templates_init to tmpl [8*256, 1024] ----------
__global__ __launch_bounds__(256) void bcast_tmpl(const float* __restrict__ tinit,
                                                  float* __restrict__ tmpl) {
  long i = (long)blockIdx.x * 256 + threadIdx.x;
  tmpl[i] = tinit[i & 262143];
}

// ---------- final attn (vectorized x4): out fp32 = bf16 attn / colsum ----------
__global__ __launch_bounds__(256) void attn_final_g(const u16* __restrict__ ab,
                                                    const float* __restrict__ cs,
                                                    float* __restrict__ out) {
  long i4 = (long)blockIdx.x * 256 + threadIdx.x;   // ushort4 index
  ushort4 v = *(const ushort4*)&ab[i4 * 4];
  float c = cs[i4 >> 10];                            // (i4*4)>>12
  float4 o;
  o.x = bf2f(v.x) / c;
  o.y = bf2f(v.y) / c;
  o.z = bf2f(v.z) / c;
  o.w = bf2f(v.w) / c;
  *(float4*)&out[i4 * 4] = o;
}

extern "C" void kernel_launch(void* const* d_in, const int* in_sizes, int n_in,
                              void* d_out, int out_size, void* d_ws, size_t ws_size,
                              hipStream_t stream) {
  const float* x       = (const float*)d_in[0];
  const float* tinit   = (const float*)d_in[1];
  const float* Wq      = (const float*)d_in[2];
  const float* Wk      = (const float*)d_in[3];
  const float* Wv      = (const float*)d_in[4];
  const float* ln_in_g = (const float*)d_in[5];
  const float* ln_in_b = (const float*)d_in[6];
  const float* ln_t_g  = (const float*)d_in[7];
  const float* ln_t_b  = (const float*)d_in[8];
  const float* ln_m_g  = (const float*)d_in[9];
  const float* ln_m_b  = (const float*)d_in[10];
  const float* W1      = (const float*)d_in[11];
  const float* b1      = (const float*)d_in[12];
  const float* W2      = (const float*)d_in[13];
  const float* b2      = (const float*)d_in[14];
  (void)in_sizes; (void)n_in; (void)out_size; (void)ws_size;

  // ---- workspace (~202 MiB peak) ----
  char* ws = (char*)d_ws;
  size_t off = 0;
  auto alloc = [&](size_t bytes) {
    void* p = ws + off;
    off += (bytes + 255) & ~(size_t)255;
    return p;
  };
  float* meanp   = (float*)alloc(32768ULL * 4);
  float* rstdp   = (float*)alloc(32768ULL * 4);
  float* ps      = (float*)alloc(262144ULL * 4);    // 8x32768 partial sums
  float* ps2     = (float*)alloc(262144ULL * 4);
  u16* xn        = (u16*)alloc(33554432ULL * 2);    // [8,4096,1024] bf16, 64 MB
  u16* vT        = (u16*)alloc(33554432ULL * 2);    // [8,1024,4096] bf16, 64 MB
  u16* attnbf    = (u16*)alloc(8388608ULL * 2);     // [8*256,4096] bf16, 16 MB
  u16* tln       = (u16*)alloc(2097152ULL * 2);     // tln / mfeat (aliased)
  u16* qk        = (u16*)alloc(2097152ULL * 2);
  u16* hidden    = (u16*)alloc(1048576ULL * 2);
  float* tmpl    = (float*)alloc(2097152ULL * 4);   // [8*256,1024] fp32
  float* Pu      = (float*)alloc(4ULL * 2097152 * 4); // 4 partial slabs, 32 MB
  u16* WqkT      = (u16*)alloc(1048576ULL * 2);     // scale*Wk*Wq^T
  u16* WvT       = (u16*)alloc(1048576ULL * 2);
  u16* W1T       = (u16*)alloc(524288ULL * 2);
  u16* W2T       = (u16*)alloc(524288ULL * 2);
  float* colsum  = (float*)alloc(2048ULL * 4);

  // temp bf16 weight casts live in attnbf slab (dead until first fls)
  u16* Wkbf = attnbf;
  u16* Wqbf = attnbf + 1048576;

  float* outT        = (float*)d_out;               // [B,D,N] 8 MB
  float* attnOutBase = (float*)d_out + 2097152;     // [B,N,L] fp32 final

  dim3 blk(256);

  ln_part<<<dim3(4096), blk, 0, stream>>>(x, ps, ps2);
  ln_red<<<dim3(128), blk, 0, stream>>>(ps, ps2, meanp, rstdp);

  // weight prep (once)
  castbf<<<dim3(4096), blk, 0, stream>>>(Wk, Wkbf);
  castbf<<<dim3(4096), blk, 0, stream>>>(Wq, Wqbf);
  mgemm<E_SCALEBF><<<dim3(8, 8, 1), blk, 0, stream>>>(
      Wkbf, Wqbf, WqkT, 1024, 1024, 1024, 1024, 0, 0, 0, nullptr, nullptr);
  tcast<<<dim3(32, 32), blk, 0, stream>>>(Wv, WvT, 1024, 1024);
  tcast<<<dim3(16, 32), blk, 0, stream>>>(W1, W1T, 1024, 512);
  tcast<<<dim3(32, 16), blk, 0, stream>>>(W2, W2T, 512, 1024);

  // all 8 batches in one pass (z = 8)
  xn_make<<<dim3(128, 32, 8), blk, 0, stream>>>(x, xn, meanp, rstdp, ln_in_g, ln_in_b);
  // vT[z][d][l] = sum_c WvT[d][c] * xn[z][l][c]
  mgemm<E_BF16><<<dim3(32, 8, 8), blk, 0, stream>>>(
      WvT, xn, vT, 1024, 1024, 1024, 4096, 0, 4194304L, 4194304L, nullptr, nullptr);
  bcast_tmpl<<<dim3(8192), blk, 0, stream>>>(tinit, tmpl);

  for (int it = 0; it < 6; ++it) {
    // t-LN (also zeros colsum for this iteration's fls)
    row_ln_bf<<<dim3(2048), blk, 0, stream>>>(tmpl, nullptr, tln, ln_t_g, ln_t_b,
                                              nullptr, colsum);
    // qk[row][c] = sum_dt tln[row][dt] * WqkT[c][dt]   (BN=64: 256 blocks)
    mgemm<E_BF16, 1, 64><<<dim3(16, 16, 1), blk, 0, stream>>>(
        tln, WqkT, qk, 1024, 1024, 1024, 1024, 0, 0, 0, nullptr, nullptr);
    // fused logits + softmax(n) + colsum -> attnbf bf16  (BNF=32: 1024 blocks)
    fls<32><<<dim3(128, 1, 8), blk, 0, stream>>>(qk, xn, attnbf, colsum);
    // P[ks] = (partial_K sum_l attn[n][l]*vT[z][d][l]) / colsum  (split-K=4,
    // plain stores, no atomics)
    mgemm<E_PART, 4><<<dim3(8, 2, 32), blk, 0, stream>>>(
        attnbf, vT, Pu, 4096, 4096, 4096, 1024, 1048576L, 4194304L, 262144L,
        nullptr, colsum);
    // m-LN fused with tmpl += sum(P): writes updated tmpl and LN -> tln
    row_ln_bf<<<dim3(2048), blk, 0, stream>>>(tmpl, tmpl, tln, ln_m_g, ln_m_b,
                                              Pu, nullptr);
    // hidden = relu(mfeat @ W1 + b1)   (BN=64: 128 blocks)
    mgemm<E_RELU, 1, 64><<<dim3(8, 16, 1), blk, 0, stream>>>(
        tln, W1T, hidden, 1024, 1024, 1024, 512, 0, 0, 0, b1, nullptr);
    // tmpl += hidden @ W2 + b2   (BN=64: 256 blocks, non-atomic)
    mgemm<E_ADDB, 1, 64><<<dim3(16, 16, 1), blk, 0, stream>>>(
        hidden, W2T, tmpl, 512, 512, 512, 1024, 0, 0, 0, b2, nullptr);
  }

  attn_final_g<<<dim3(8192), blk, 0, stream>>>(attnbf, colsum, attnOutBase);
  transpose_f32<<<dim3(32, 8, 8), blk, 0, stream>>>(
      tmpl, outT, 256, 1024, 262144L, 262144L);
}

// Round 13
// 1213.685 us; speedup vs baseline: 1.0743x; 1.0743x over previous
//
#include <hip/hip_runtime.h>

#define EPS_ 1e-5f
#define SCALE_ 0.03125f   // DIM^-0.5 = 1/32

typedef __attribute__((ext_vector_type(8))) short short8;
typedef __attribute__((ext_vector_type(4))) float f32x4;
typedef unsigned short u16;

__device__ __forceinline__ float bf2f(u16 s) {
  return __uint_as_float(((unsigned int)s) << 16);
}
__device__ __forceinline__ u16 f2bf(float f) {
  unsigned int u = __float_as_uint(f);
  unsigned int r = 0x7FFFu + ((u >> 16) & 1u);
  return (u16)((u + r) >> 16);
}

// async global->LDS, 16B per lane; LDS dest must be linear in lane order
__device__ __forceinline__ void gload16(const void* g, void* l) {
  __builtin_amdgcn_global_load_lds(
      (const __attribute__((address_space(1))) unsigned int*)g,
      (__attribute__((address_space(3))) unsigned int*)l, 16, 0, 0);
}

// ---------- LN stats stage 1: partial sums per (c-chunk, row) ----------
__global__ __launch_bounds__(256) void ln_part(const float* __restrict__ x,
                                               float* __restrict__ ps,
                                               float* __restrict__ ps2) {
  int tl = threadIdx.x & 63;
  int cg = threadIdx.x >> 6;             // 0..3
  int lblk = blockIdx.x >> 3;
  int cchunk = blockIdx.x & 7;
  int row = lblk * 64 + tl;              // b*4096 + l
  int bb = row >> 12, l = row & 4095;
  const float* xp = x + (long)bb * 4194304L + l;
  int c0 = cchunk * 128 + cg;
  float s = 0.f, s2 = 0.f;
#pragma unroll
  for (int i = 0; i < 32; ++i) {
    float v = xp[(long)(c0 + i * 4) * 4096];
    s += v; s2 += v * v;
  }
  __shared__ float sh[2][4][64];
  sh[0][cg][tl] = s; sh[1][cg][tl] = s2;
  __syncthreads();
  if (threadIdx.x < 64) {
    float ts = sh[0][0][tl] + sh[0][1][tl] + sh[0][2][tl] + sh[0][3][tl];
    float t2 = sh[1][0][tl] + sh[1][1][tl] + sh[1][2][tl] + sh[1][3][tl];
    ps[cchunk * 32768 + row] = ts;
    ps2[cchunk * 32768 + row] = t2;
  }
}

// ---------- LN stats stage 2: reduce 8 chunks -> mean/rstd ----------
__global__ __launch_bounds__(256) void ln_red(const float* __restrict__ ps,
                                              const float* __restrict__ ps2,
                                              float* __restrict__ meanp,
                                              float* __restrict__ rstdp) {
  int row = blockIdx.x * 256 + threadIdx.x;
  float s = 0.f, s2 = 0.f;
#pragma unroll
  for (int k = 0; k < 8; ++k) {
    s += ps[k * 32768 + row];
    s2 += ps2[k * 32768 + row];
  }
  float mu = s * (1.0f / 1024.0f);
  float var = s2 * (1.0f / 1024.0f) - mu * mu;
  meanp[row] = mu;
  rstdp[row] = rsqrtf(var + EPS_);
}

// ---------- xn[b][l][c] = bf16(LN(x[b][c][l])) via LDS tile transpose ----------
__global__ __launch_bounds__(256) void xn_make(const float* __restrict__ x,
                                               u16* __restrict__ xn,
                                               const float* __restrict__ meanp,
                                               const float* __restrict__ rstdp,
                                               const float* __restrict__ g,
                                               const float* __restrict__ beta) {
  __shared__ float tile[32][33];
  int b = blockIdx.z;
  int ct = blockIdx.y * 32;
  int lt = blockIdx.x * 32;
  int tx = threadIdx.x & 31, ty = threadIdx.x >> 5;
  const float* xp = x + (long)b * 4194304;
  int l = lt + tx;
  float mu = meanp[(b << 12) + l];
  float rs = rstdp[(b << 12) + l];
#pragma unroll
  for (int k = 0; k < 32; k += 8) {
    int c = ct + ty + k;
    float v = xp[(long)c * 4096 + l];
    tile[ty + k][tx] = (v - mu) * rs * g[c] + beta[c];
  }
  __syncthreads();
  u16* xq = xn + (long)b * 4194304;
#pragma unroll
  for (int k = 0; k < 32; k += 8) {
    int ll = lt + ty + k;
    xq[(long)ll * 1024 + ct + tx] = f2bf(tile[tx][ty + k]);
  }
}

// ---------- fp32 transpose (templates out): dst[z][c][r] = src[z][r][c] ----------
__global__ __launch_bounds__(256) void transpose_f32(const float* __restrict__ src,
                                                     float* __restrict__ dst,
                                                     int R, int Cc, long sSrc, long sDst) {
  __shared__ float tile[32][33];
  int z = blockIdx.z;
  int rt = blockIdx.y * 32, ct = blockIdx.x * 32;
  int tx = threadIdx.x & 31, ty = threadIdx.x >> 5;
  const float* s = src + (long)z * sSrc;
  float* d = dst + (long)z * sDst;
#pragma unroll
  for (int k = 0; k < 32; k += 8) tile[ty + k][tx] = s[(long)(rt + ty + k) * Cc + ct + tx];
  __syncthreads();
#pragma unroll
  for (int k = 0; k < 32; k += 8) d[(long)(ct + ty + k) * R + rt + tx] = tile[tx][ty + k];
}

// ---------- transpose + cast fp32 [R,C] -> bf16 [C,R] ----------
__global__ __launch_bounds__(256) void tcast(const float* __restrict__ src,
                                             u16* __restrict__ dst, int R, int C) {
  __shared__ float tile[32][33];
  int rt = blockIdx.y * 32, ct = blockIdx.x * 32;
  int tx = threadIdx.x & 31, ty = threadIdx.x >> 5;
#pragma unroll
  for (int k = 0; k < 32; k += 8) tile[ty + k][tx] = src[(long)(rt + ty + k) * C + ct + tx];
  __syncthreads();
#pragma unroll
  for (int k = 0; k < 32; k += 8) dst[(long)(ct + ty + k) * R + rt + tx] = f2bf(tile[tx][ty + k]);
}

// ---------- elementwise cast fp32 -> bf16 ----------
__global__ __launch_bounds__(256) void castbf(const float* __restrict__ in,
                                              u16* __restrict__ out) {
  long i = (long)blockIdx.x * 256 + threadIdx.x;
  out[i] = f2bf(in[i]);
}

// ---------- MFMA NT GEMM: C[m][n] = sum_k A[m][k]*Bt[n][k], bf16 in, fp32 acc ----
// BM=128, BN=128 or 64 (template), BK=64, 256 thr (4 waves).
// 2-phase double-buffered staging + XOR-swizzled LDS (rule #21).
// E_PART: atomic-free split-K partial slabs (stride 2^21 floats).
enum { E_BF16 = 0, E_SCALEBF = 1, E_F32 = 2, E_PART = 3, E_RELU = 4, E_ADDB = 5 };

template <int EPI, int KSPLIT = 1, int BN = 128>
__global__ __launch_bounds__(256) void mgemm(
    const u16* __restrict__ A, const u16* __restrict__ Bt, void* __restrict__ Cv,
    int K, int lda, int ldb, int ldc, long sA, long sB, long sC,
    const float* __restrict__ bias, const float* __restrict__ colsum) {
  __shared__ u16 Als[2][128 * 64];
  __shared__ u16 Bls[2][BN * 64];
  constexpr int NJ = BN / 32;     // B-fragments per wave (4 or 2)
  constexpr int NBS = BN / 32;    // B staging chunks per thread (4 or 2)
  const int tid = threadIdx.x;
  const int zb = (KSPLIT == 1) ? blockIdx.z : blockIdx.z / KSPLIT;
  const int ks = (KSPLIT == 1) ? 0 : blockIdx.z % KSPLIT;
  const int bm = blockIdx.y * 128;
  const int bn = blockIdx.x * BN;
  A += (long)zb * sA;
  Bt += (long)zb * sB;
  const int kpart = K / KSPLIT;
  const int kbase = ks * kpart;
  const int lane = tid & 63;
  const int w = tid >> 6;
  const int wm = (w & 1) * 64;
  const int wn = (w >> 1) * (BN / 2);
  const int fr = lane & 15;
  const int fq = lane >> 4;
  const int frx = fr & 7;                 // read-side XOR key (row&7 == fr&7)
  f32x4 acc[4][NJ] = {};

  const int srow = tid >> 3;
  // source chunk pre-swizzle: LDS chunk (tid&7) <- global chunk (tid&7)^(row&7)
  const int sko = (((tid & 7) ^ (srow & 7)) << 3);
  const u16* Ag = A + (long)(bm + srow) * lda + kbase + sko;
  const u16* Bg = Bt + (long)(bn + srow) * ldb + kbase + sko;
  const long astep = 32L * lda;
  const long bstep = 32L * ldb;

#define STAGE_(bufI, kOff)                                                   \
  {                                                                          \
    _Pragma("unroll") for (int i_ = 0; i_ < 4; ++i_)                         \
      gload16(Ag + i_ * astep + (kOff), &Als[bufI][tid * 8 + i_ * 2048]);    \
    _Pragma("unroll") for (int i_ = 0; i_ < NBS; ++i_)                       \
      gload16(Bg + i_ * bstep + (kOff), &Bls[bufI][tid * 8 + i_ * 2048]);    \
  }

#define COMPUTE_(bufI)                                                       \
  {                                                                          \
    _Pragma("unroll") for (int kc = 0; kc < 2; ++kc) {                       \
      const int kx = ((kc * 4 + fq) ^ frx) << 3;                             \
      short8 af[4], bv[NJ];                                                  \
      _Pragma("unroll") for (int i = 0; i < 4; ++i)                          \
          af[i] = *(const short8*)&Als[bufI][(wm + i * 16 + fr) * 64 + kx];  \
      _Pragma("unroll") for (int j = 0; j < NJ; ++j)                         \
          bv[j] = *(const short8*)&Bls[bufI][(wn + j * 16 + fr) * 64 + kx];  \
      _Pragma("unroll") for (int i = 0; i < 4; ++i)                          \
          _Pragma("unroll") for (int j = 0; j < NJ; ++j)                     \
              acc[i][j] = __builtin_amdgcn_mfma_f32_16x16x32_bf16(           \
                  af[i], bv[j], acc[i][j], 0, 0, 0);                         \
    }                                                                        \
  }

  const int nsteps = kpart >> 6;   // even at all call sites (8/16)
  STAGE_(0, 0);
  __syncthreads();
  for (int s = 0; s < nsteps - 2; s += 2) {
    STAGE_(1, (s + 1) * 64);
    COMPUTE_(0);
    __syncthreads();
    STAGE_(0, (s + 2) * 64);
    COMPUTE_(1);
    __syncthreads();
  }
  STAGE_(1, (nsteps - 1) * 64);
  COMPUTE_(0);
  __syncthreads();
  COMPUTE_(1);
#undef STAGE_
#undef COMPUTE_

  // C/D frag mapping: col = lane&15, row = (lane>>4)*4 + r
#pragma unroll
  for (int i = 0; i < 4; ++i) {
#pragma unroll
    for (int j = 0; j < NJ; ++j) {
      int gc = bn + wn + j * 16 + fr;
#pragma unroll
      for (int r = 0; r < 4; ++r) {
        int gr = bm + wm + i * 16 + fq * 4 + r;
        float v = acc[i][j][r];
        if constexpr (EPI == E_BF16) {
          ((u16*)Cv + (long)zb * sC)[(long)gr * ldc + gc] = f2bf(v);
        } else if constexpr (EPI == E_SCALEBF) {
          ((u16*)Cv + (long)zb * sC)[(long)gr * ldc + gc] = f2bf(v * SCALE_);
        } else if constexpr (EPI == E_F32) {
          ((float*)Cv + (long)zb * sC)[(long)gr * ldc + gc] = v;
        } else if constexpr (EPI == E_PART) {
          // plain store of normalized partial into slab ks (stride 2^21 floats)
          float* C = (float*)Cv + ((long)ks << 21) + (long)zb * sC;
          C[(long)gr * ldc + gc] = v * (1.0f / colsum[zb * 256 + gr]);
        } else if constexpr (EPI == E_RELU) {
          float h = v + bias[gc];
          ((u16*)Cv + (long)zb * sC)[(long)gr * ldc + gc] = f2bf(h > 0.f ? h : 0.f);
        } else {  // E_ADDB (non-atomic, KSPLIT==1 only)
          float* C = (float*)Cv + (long)zb * sC;
          C[(long)gr * ldc + gc] += v + bias[gc];
        }
      }
    }
  }
}

// ---------- fused logits GEMM + softmax(n) + colsum ----------
// BM=256 (all n slots), BNF-wide l-tile (template), K=1024. 4 waves in M.
// Single-buffered (verified structure), BNF=64: 512 blocks, 40 KB LDS.
// BNF=32 measured WORSE (r12: stage-throughput-bound; halving per-step MFMA
// while keeping A-stage cost doubled gloads/MFMA). BNF=64 is the optimum.
template <int BNF>
__global__ __launch_bounds__(256) void fls(const u16* __restrict__ qk,
                                           const u16* __restrict__ xn,
                                           u16* __restrict__ attnbf,
                                           float* __restrict__ colsum) {
  __shared__ u16 Als[256 * 64];    // 32 KB, qk rows (n)
  __shared__ u16 Bls[BNF * 64];    // xn rows (l)
  __shared__ float sred[4][BNF];
  __shared__ float ssum[4][BNF];
  constexpr int NJ = BNF / 16;     // l-fragments per lane-col group
  constexpr int NBS = BNF / 32;    // B staging gloads
  const int tid = threadIdx.x;
  const int z = blockIdx.z;
  const int l0 = blockIdx.x * BNF;
  const u16* A = qk + (long)z * 262144;     // [256][1024]
  const u16* B = xn + (long)z * 4194304;    // [4096][1024]
  const int lane = tid & 63;
  const int w = tid >> 6;
  const int wm = w * 64;
  const int fr = lane & 15, fq = lane >> 4;
  const int frx = fr & 7;
  f32x4 acc[4][NJ] = {};

  const int srow = tid >> 3;
  const int sko = (((tid & 7) ^ (srow & 7)) << 3);
  const u16* Ag = A + (long)srow * 1024 + sko;
  const u16* Bg = B + (long)(l0 + srow) * 1024 + sko;
  u16* Al = Als + tid * 8;
  u16* Bl = Bls + tid * 8;

  for (int k0 = 0; k0 < 1024; k0 += 64) {
#pragma unroll
    for (int i = 0; i < 8; ++i)
      gload16(Ag + (long)i * 32768 + k0, Al + i * 2048);
#pragma unroll
    for (int i = 0; i < NBS; ++i)
      gload16(Bg + (long)i * 32768 + k0, Bl + i * 2048);
    __syncthreads();
#pragma unroll
    for (int kc = 0; kc < 2; ++kc) {
      const int kx = ((kc * 4 + fq) ^ frx) << 3;
      short8 af[4], bf[NJ];
#pragma unroll
      for (int i = 0; i < 4; ++i)
        af[i] = *(const short8*)&Als[(wm + i * 16 + fr) * 64 + kx];
#pragma unroll
      for (int j = 0; j < NJ; ++j)
        bf[j] = *(const short8*)&Bls[(j * 16 + fr) * 64 + kx];
#pragma unroll
      for (int i = 0; i < 4; ++i)
#pragma unroll
        for (int j = 0; j < NJ; ++j)
          acc[i][j] = __builtin_amdgcn_mfma_f32_16x16x32_bf16(af[i], bf[j], acc[i][j], 0, 0, 0);
    }
    __syncthreads();
  }

  // ---- softmax over n (256) per l-col; lane holds rows (i,r) of cols (j,fr)
  float mj[NJ];
#pragma unroll
  for (int j = 0; j < NJ; ++j) {
    float m = acc[0][j][0];
#pragma unroll
    for (int i = 0; i < 4; ++i)
#pragma unroll
      for (int r = 0; r < 4; ++r) m = fmaxf(m, acc[i][j][r]);
    m = fmaxf(m, __shfl_xor(m, 16));
    m = fmaxf(m, __shfl_xor(m, 32));
    mj[j] = m;
  }
  if (fq == 0) {
#pragma unroll
    for (int j = 0; j < NJ; ++j) sred[w][j * 16 + fr] = mj[j];
  }
  __syncthreads();
  float M4[NJ];
#pragma unroll
  for (int j = 0; j < NJ; ++j) {
    int c = j * 16 + fr;
    M4[j] = fmaxf(fmaxf(sred[0][c], sred[1][c]), fmaxf(sred[2][c], sred[3][c]));
  }
  float pj[NJ];
#pragma unroll
  for (int j = 0; j < NJ; ++j) pj[j] = 0.f;
#pragma unroll
  for (int i = 0; i < 4; ++i)
#pragma unroll
    for (int j = 0; j < NJ; ++j)
#pragma unroll
      for (int r = 0; r < 4; ++r) {
        float e = __expf(acc[i][j][r] - M4[j]);
        acc[i][j][r] = e;
        pj[j] += e;
      }
#pragma unroll
  for (int j = 0; j < NJ; ++j) {
    pj[j] += __shfl_xor(pj[j], 16);
    pj[j] += __shfl_xor(pj[j], 32);
  }
  if (fq == 0) {
#pragma unroll
    for (int j = 0; j < NJ; ++j) ssum[w][j * 16 + fr] = pj[j];
  }
  __syncthreads();
  float inv[NJ];
#pragma unroll
  for (int j = 0; j < NJ; ++j) {
    int c = j * 16 + fr;
    inv[j] = 1.0f / (ssum[0][c] + ssum[1][c] + ssum[2][c] + ssum[3][c]);
  }
  // ---- write bf16 attn + colsum partials
  u16* outp = attnbf + (long)z * 1048576;
#pragma unroll
  for (int i = 0; i < 4; ++i) {
#pragma unroll
    for (int r = 0; r < 4; ++r) {
      int n = wm + i * 16 + fq * 4 + r;
      float cs = 0.f;
#pragma unroll
      for (int j = 0; j < NJ; ++j) {
        float a = acc[i][j][r] * inv[j] + 1e-8f;
        u16 ab = f2bf(a);
        outp[(long)n * 4096 + l0 + j * 16 + fr] = ab;
        cs += bf2f(ab);
      }
      cs += __shfl_xor(cs, 1);
      cs += __shfl_xor(cs, 2);
      cs += __shfl_xor(cs, 4);
      cs += __shfl_xor(cs, 8);
      if (fr == 0) atomicAdd(&colsum[z * 256 + n], cs);
    }
  }
}

// ---------- row LN over D=1024, fp32 in -> bf16 out ----------
// part != null: xv = in + sum of 4 partial slabs (stride 2^21), write back to
// tupd (the updated templates), then LN.  cz != null: zero colsum.
__global__ __launch_bounds__(256) void row_ln_bf(const float* in,
                                                 float* tupd,
                                                 u16* __restrict__ out,
                                                 const float* __restrict__ g,
                                                 const float* __restrict__ bvec,
                                                 const float* part,
                                                 float* __restrict__ cz) {
  if (cz && blockIdx.x < 8) cz[blockIdx.x * 256 + threadIdx.x] = 0.f;
  long base = (long)blockIdx.x * 1024;
  int c = threadIdx.x << 2;
  float4 xv = *(const float4*)&in[base + c];
  if (part) {
    const float* p = part + base + c;
    float4 a0 = *(const float4*)(p);
    float4 a1 = *(const float4*)(p + 2097152);
    float4 a2 = *(const float4*)(p + 4194304);
    float4 a3 = *(const float4*)(p + 6291456);
    xv.x += a0.x + a1.x + a2.x + a3.x;
    xv.y += a0.y + a1.y + a2.y + a3.y;
    xv.z += a0.z + a1.z + a2.z + a3.z;
    xv.w += a0.w + a1.w + a2.w + a3.w;
    *(float4*)&tupd[base + c] = xv;
  }
  float s = xv.x + xv.y + xv.z + xv.w;
  float s2 = xv.x * xv.x + xv.y * xv.y + xv.z * xv.z + xv.w * xv.w;
#pragma unroll
  for (int off = 32; off > 0; off >>= 1) {
    s += __shfl_down(s, off);
    s2 += __shfl_down(s2, off);
  }
  __shared__ float sh[8];
  if ((threadIdx.x & 63) == 0) {
    sh[threadIdx.x >> 6] = s;
    sh[4 + (threadIdx.x >> 6)] = s2;
  }
  __syncthreads();
  float ts = sh[0] + sh[1] + sh[2] + sh[3];
  float t2 = sh[4] + sh[5] + sh[6] + sh[7];
  float mu = ts * (1.0f / 1024.0f);
  float rs = rsqrtf(t2 * (1.0f / 1024.0f) - mu * mu + EPS_);
  ushort4 o;
  o.x = f2bf((xv.x - mu) * rs * g[c + 0] + bvec[c + 0]);
  o.y = f2bf((xv.y - mu) * rs * g[c + 1] + bvec[c + 1]);
  o.z = f2bf((xv.z - mu) * rs * g[c + 2] + bvec[c + 2]);
  o.w = f2bf((xv.w - mu) * rs * g[c + 3] + bvec[c + 3]);
  *(ushort4*)&out[base + c] = o;
}

// ---------- broadcast templates_init to tmpl [8*256, 1024] ----------
__global__ __launch_bounds__(256) void bcast_tmpl(const float* __restrict__ tinit,
                                                  float* __restrict__ tmpl) {
  long i = (long)blockIdx.x * 256 + threadIdx.x;
  tmpl[i] = tinit[i & 262143];
}

// ---------- final attn (vectorized x4): out fp32 = bf16 attn / colsum ----------
__global__ __launch_bounds__(256) void attn_final_g(const u16* __restrict__ ab,
                                                    const float* __restrict__ cs,
                                                    float* __restrict__ out) {
  long i4 = (long)blockIdx.x * 256 + threadIdx.x;   // ushort4 index
  ushort4 v = *(const ushort4*)&ab[i4 * 4];
  float c = cs[i4 >> 10];                            // (i4*4)>>12
  float4 o;
  o.x = bf2f(v.x) / c;
  o.y = bf2f(v.y) / c;
  o.z = bf2f(v.z) / c;
  o.w = bf2f(v.w) / c;
  *(float4*)&out[i4 * 4] = o;
}

extern "C" void kernel_launch(void* const* d_in, const int* in_sizes, int n_in,
                              void* d_out, int out_size, void* d_ws, size_t ws_size,
                              hipStream_t stream) {
  const float* x       = (const float*)d_in[0];
  const float* tinit   = (const float*)d_in[1];
  const float* Wq      = (const float*)d_in[2];
  const float* Wk      = (const float*)d_in[3];
  const float* Wv      = (const float*)d_in[4];
  const float* ln_in_g = (const float*)d_in[5];
  const float* ln_in_b = (const float*)d_in[6];
  const float* ln_t_g  = (const float*)d_in[7];
  const float* ln_t_b  = (const float*)d_in[8];
  const float* ln_m_g  = (const float*)d_in[9];
  const float* ln_m_b  = (const float*)d_in[10];
  const float* W1      = (const float*)d_in[11];
  const float* b1      = (const float*)d_in[12];
  const float* W2      = (const float*)d_in[13];
  const float* b2      = (const float*)d_in[14];
  (void)in_sizes; (void)n_in; (void)out_size; (void)ws_size;

  // ---- workspace (~202 MiB peak) ----
  char* ws = (char*)d_ws;
  size_t off = 0;
  auto alloc = [&](size_t bytes) {
    void* p = ws + off;
    off += (bytes + 255) & ~(size_t)255;
    return p;
  };
  float* meanp   = (float*)alloc(32768ULL * 4);
  float* rstdp   = (float*)alloc(32768ULL * 4);
  float* ps      = (float*)alloc(262144ULL * 4);    // 8x32768 partial sums
  float* ps2     = (float*)alloc(262144ULL * 4);
  u16* xn        = (u16*)alloc(33554432ULL * 2);    // [8,4096,1024] bf16, 64 MB
  u16* vT        = (u16*)alloc(33554432ULL * 2);    // [8,1024,4096] bf16, 64 MB
  u16* attnbf    = (u16*)alloc(8388608ULL * 2);     // [8*256,4096] bf16, 16 MB
  u16* tln       = (u16*)alloc(2097152ULL * 2);     // tln / mfeat (aliased)
  u16* qk        = (u16*)alloc(2097152ULL * 2);
  u16* hidden    = (u16*)alloc(1048576ULL * 2);
  float* tmpl    = (float*)alloc(2097152ULL * 4);   // [8*256,1024] fp32
  float* Pu      = (float*)alloc(4ULL * 2097152 * 4); // 4 partial slabs, 32 MB
  u16* WqkT      = (u16*)alloc(1048576ULL * 2);     // scale*Wk*Wq^T
  u16* WvT       = (u16*)alloc(1048576ULL * 2);
  u16* W1T       = (u16*)alloc(524288ULL * 2);
  u16* W2T       = (u16*)alloc(524288ULL * 2);
  float* colsum  = (float*)alloc(2048ULL * 4);

  // temp bf16 weight casts live in attnbf slab (dead until first fls)
  u16* Wkbf = attnbf;
  u16* Wqbf = attnbf + 1048576;

  float* outT        = (float*)d_out;               // [B,D,N] 8 MB
  float* attnOutBase = (float*)d_out + 2097152;     // [B,N,L] fp32 final

  dim3 blk(256);

  ln_part<<<dim3(4096), blk, 0, stream>>>(x, ps, ps2);
  ln_red<<<dim3(128), blk, 0, stream>>>(ps, ps2, meanp, rstdp);

  // weight prep (once)
  castbf<<<dim3(4096), blk, 0, stream>>>(Wk, Wkbf);
  castbf<<<dim3(4096), blk, 0, stream>>>(Wq, Wqbf);
  mgemm<E_SCALEBF><<<dim3(8, 8, 1), blk, 0, stream>>>(
      Wkbf, Wqbf, WqkT, 1024, 1024, 1024, 1024, 0, 0, 0, nullptr, nullptr);
  tcast<<<dim3(32, 32), blk, 0, stream>>>(Wv, WvT, 1024, 1024);
  tcast<<<dim3(16, 32), blk, 0, stream>>>(W1, W1T, 1024, 512);
  tcast<<<dim3(32, 16), blk, 0, stream>>>(W2, W2T, 512, 1024);

  // all 8 batches in one pass (z = 8)
  xn_make<<<dim3(128, 32, 8), blk, 0, stream>>>(x, xn, meanp, rstdp, ln_in_g, ln_in_b);
  // vT[z][d][l] = sum_c WvT[d][c] * xn[z][l][c]
  mgemm<E_BF16><<<dim3(32, 8, 8), blk, 0, stream>>>(
      WvT, xn, vT, 1024, 1024, 1024, 4096, 0, 4194304L, 4194304L, nullptr, nullptr);
  bcast_tmpl<<<dim3(8192), blk, 0, stream>>>(tinit, tmpl);

  for (int it = 0; it < 6; ++it) {
    // t-LN (also zeros colsum for this iteration's fls)
    row_ln_bf<<<dim3(2048), blk, 0, stream>>>(tmpl, nullptr, tln, ln_t_g, ln_t_b,
                                              nullptr, colsum);
    // qk[row][c] = sum_dt tln[row][dt] * WqkT[c][dt]   (BN=64: 256 blocks)
    mgemm<E_BF16, 1, 64><<<dim3(16, 16, 1), blk, 0, stream>>>(
        tln, WqkT, qk, 1024, 1024, 1024, 1024, 0, 0, 0, nullptr, nullptr);
    // fused logits + softmax(n) + colsum -> attnbf bf16  (BNF=64: 512 blocks)
    fls<64><<<dim3(64, 1, 8), blk, 0, stream>>>(qk, xn, attnbf, colsum);
    // P[ks] = (partial_K sum_l attn[n][l]*vT[z][d][l]) / colsum  (split-K=4,
    // plain stores, no atomics)
    mgemm<E_PART, 4><<<dim3(8, 2, 32), blk, 0, stream>>>(
        attnbf, vT, Pu, 4096, 4096, 4096, 1024, 1048576L, 4194304L, 262144L,
        nullptr, colsum);
    // m-LN fused with tmpl += sum(P): writes updated tmpl and LN -> tln
    row_ln_bf<<<dim3(2048), blk, 0, stream>>>(tmpl, tmpl, tln, ln_m_g, ln_m_b,
                                              Pu, nullptr);
    // hidden = relu(mfeat @ W1 + b1)   (BN=64: 128 blocks)
    mgemm<E_RELU, 1, 64><<<dim3(8, 16, 1), blk, 0, stream>>>(
        tln, W1T, hidden, 1024, 1024, 1024, 512, 0, 0, 0, b1, nullptr);
    // tmpl += hidden @ W2 + b2   (BN=64: 256 blocks, non-atomic)
    mgemm<E_ADDB, 1, 64><<<dim3(16, 16, 1), blk, 0, stream>>>(
        hidden, W2T, tmpl, 512, 512, 512, 1024, 0, 0, 0, b2, nullptr);
  }

  attn_final_g<<<dim3(8192), blk, 0, stream>>>(attnbf, colsum, attnOutBase);
  transpose_f32<<<dim3(32, 8, 8), blk, 0, stream>>>(
      tmpl, outT, 256, 1024, 262144L, 262144L);
}

// Round 14
// 1186.689 us; speedup vs baseline: 1.0988x; 1.0227x over previous
//
#include <hip/hip_runtime.h>

#define EPS_ 1e-5f
#define SCALE_ 0.03125f   // DIM^-0.5 = 1/32

typedef __attribute__((ext_vector_type(8))) short short8;
typedef __attribute__((ext_vector_type(4))) float f32x4;
typedef unsigned short u16;

__device__ __forceinline__ float bf2f(u16 s) {
  return __uint_as_float(((unsigned int)s) << 16);
}
__device__ __forceinline__ u16 f2bf(float f) {
  unsigned int u = __float_as_uint(f);
  unsigned int r = 0x7FFFu + ((u >> 16) & 1u);
  return (u16)((u + r) >> 16);
}

// async global->LDS, 16B per lane; LDS dest must be linear in lane order
__device__ __forceinline__ void gload16(const void* g, void* l) {
  __builtin_amdgcn_global_load_lds(
      (const __attribute__((address_space(1))) unsigned int*)g,
      (__attribute__((address_space(3))) unsigned int*)l, 16, 0, 0);
}

// ---------- fused setup stage 1 (independent blocks, branch by blockIdx) ----
// [0,4096)        : ln_part  — partial LN sums per (c-chunk, 64-row band)
// [4096,12288)    : castbf Wk / Wq -> bf16
// [12288,14336)   : tcast Wv (1024), W1 (512), W2 (512)
__global__ __launch_bounds__(256) void setup1(
    const float* __restrict__ x, float* __restrict__ ps, float* __restrict__ ps2,
    const float* __restrict__ Wk, const float* __restrict__ Wq,
    u16* __restrict__ Wkbf, u16* __restrict__ Wqbf,
    const float* __restrict__ Wv, const float* __restrict__ W1,
    const float* __restrict__ W2,
    u16* __restrict__ WvT, u16* __restrict__ W1T, u16* __restrict__ W2T) {
  __shared__ float shmem[1056];   // union: ln sums (512 f) or 32x33 tile (1056 f)
  const int b = blockIdx.x;
  const int t = threadIdx.x;
  if (b < 4096) {
    // ---- ln_part ----
    int tl = t & 63;
    int cg = t >> 6;               // 0..3
    int cchunk = b & 7;
    int row = (b >> 3) * 64 + tl;  // bb*4096 + l
    int bb = row >> 12, l = row & 4095;
    const float* xp = x + (long)bb * 4194304L + l;
    int c0 = cchunk * 128 + cg;
    float s = 0.f, s2 = 0.f;
#pragma unroll
    for (int i = 0; i < 32; ++i) {
      float v = xp[(long)(c0 + i * 4) * 4096];
      s += v; s2 += v * v;
    }
    shmem[cg * 64 + tl] = s;
    shmem[256 + cg * 64 + tl] = s2;
    __syncthreads();
    if (t < 64) {
      float ts = shmem[t] + shmem[64 + t] + shmem[128 + t] + shmem[192 + t];
      float t2 = shmem[256 + t] + shmem[320 + t] + shmem[384 + t] + shmem[448 + t];
      int row0 = (b >> 3) * 64 + t;
      ps[cchunk * 32768 + row0] = ts;
      ps2[cchunk * 32768 + row0] = t2;
    }
  } else if (b < 12288) {
    // ---- castbf ----
    long i = (long)((b - 4096) & 4095) * 256 + t;
    if (b < 8192) Wkbf[i] = f2bf(Wk[i]);
    else          Wqbf[i] = f2bf(Wq[i]);
  } else {
    // ---- tcast fp32 [R,C] -> bf16 [C,R] ----
    int r = b - 12288;
    const float* src; u16* dst; int R, C, bx, by;
    if (r < 1024)      { src = Wv; dst = WvT; R = 1024; C = 1024; bx = r & 31; by = r >> 5; }
    else if (r < 1536) { int q = r - 1024; src = W1; dst = W1T; R = 1024; C = 512; bx = q & 15; by = q >> 4; }
    else               { int q = r - 1536; src = W2; dst = W2T; R = 512; C = 1024; bx = q & 31; by = q >> 5; }
    float (*tile)[33] = (float(*)[33])shmem;
    int rt = by * 32, ct = bx * 32;
    int tx = t & 31, ty = t >> 5;
#pragma unroll
    for (int k = 0; k < 32; k += 8) tile[ty + k][tx] = src[(long)(rt + ty + k) * C + ct + tx];
    __syncthreads();
#pragma unroll
    for (int k = 0; k < 32; k += 8) dst[(long)(ct + ty + k) * R + rt + tx] = f2bf(tile[tx][ty + k]);
  }
}

// ---------- fused setup stage 2: bcast tmpl (all 8192 blocks) + ln_red (<128) -
__global__ __launch_bounds__(256) void setup2(const float* __restrict__ ps,
                                              const float* __restrict__ ps2,
                                              float* __restrict__ meanp,
                                              float* __restrict__ rstdp,
                                              const float* __restrict__ tinit,
                                              float* __restrict__ tmpl) {
  long i = (long)blockIdx.x * 256 + threadIdx.x;
  tmpl[i] = tinit[i & 262143];
  if (blockIdx.x < 128) {
    int row = blockIdx.x * 256 + threadIdx.x;
    float s = 0.f, s2 = 0.f;
#pragma unroll
    for (int k = 0; k < 8; ++k) {
      s += ps[k * 32768 + row];
      s2 += ps2[k * 32768 + row];
    }
    float mu = s * (1.0f / 1024.0f);
    float var = s2 * (1.0f / 1024.0f) - mu * mu;
    meanp[row] = mu;
    rstdp[row] = rsqrtf(var + EPS_);
  }
}

// ---------- xn[b][l][c] = bf16(LN(x[b][c][l])) via LDS tile transpose ----------
__global__ __launch_bounds__(256) void xn_make(const float* __restrict__ x,
                                               u16* __restrict__ xn,
                                               const float* __restrict__ meanp,
                                               const float* __restrict__ rstdp,
                                               const float* __restrict__ g,
                                               const float* __restrict__ beta) {
  __shared__ float tile[32][33];
  int b = blockIdx.z;
  int ct = blockIdx.y * 32;
  int lt = blockIdx.x * 32;
  int tx = threadIdx.x & 31, ty = threadIdx.x >> 5;
  const float* xp = x + (long)b * 4194304;
  int l = lt + tx;
  float mu = meanp[(b << 12) + l];
  float rs = rstdp[(b << 12) + l];
#pragma unroll
  for (int k = 0; k < 32; k += 8) {
    int c = ct + ty + k;
    float v = xp[(long)c * 4096 + l];
    tile[ty + k][tx] = (v - mu) * rs * g[c] + beta[c];
  }
  __syncthreads();
  u16* xq = xn + (long)b * 4194304;
#pragma unroll
  for (int k = 0; k < 32; k += 8) {
    int ll = lt + ty + k;
    xq[(long)ll * 1024 + ct + tx] = f2bf(tile[tx][ty + k]);
  }
}

// ---------- MFMA NT GEMM: C[m][n] = sum_k A[m][k]*Bt[n][k], bf16 in, fp32 acc ----
// BM=128, BN=128 or 64 (template), BK=64, 256 thr (4 waves).
// 2-phase double-buffered staging + XOR-swizzled LDS (rule #21).
// E_PART: atomic-free split-K partial slabs (stride 2^21 floats).
enum { E_BF16 = 0, E_SCALEBF = 1, E_F32 = 2, E_PART = 3, E_RELU = 4, E_ADDB = 5 };

template <int EPI, int KSPLIT = 1, int BN = 128>
__global__ __launch_bounds__(256) void mgemm(
    const u16* __restrict__ A, const u16* __restrict__ Bt, void* __restrict__ Cv,
    int K, int lda, int ldb, int ldc, long sA, long sB, long sC,
    const float* __restrict__ bias, const float* __restrict__ colsum) {
  __shared__ u16 Als[2][128 * 64];
  __shared__ u16 Bls[2][BN * 64];
  constexpr int NJ = BN / 32;     // B-fragments per wave (4 or 2)
  constexpr int NBS = BN / 32;    // B staging chunks per thread (4 or 2)
  const int tid = threadIdx.x;
  const int zb = (KSPLIT == 1) ? blockIdx.z : blockIdx.z / KSPLIT;
  const int ks = (KSPLIT == 1) ? 0 : blockIdx.z % KSPLIT;
  const int bm = blockIdx.y * 128;
  const int bn = blockIdx.x * BN;
  A += (long)zb * sA;
  Bt += (long)zb * sB;
  const int kpart = K / KSPLIT;
  const int kbase = ks * kpart;
  const int lane = tid & 63;
  const int w = tid >> 6;
  const int wm = (w & 1) * 64;
  const int wn = (w >> 1) * (BN / 2);
  const int fr = lane & 15;
  const int fq = lane >> 4;
  const int frx = fr & 7;                 // read-side XOR key (row&7 == fr&7)
  f32x4 acc[4][NJ] = {};

  const int srow = tid >> 3;
  // source chunk pre-swizzle: LDS chunk (tid&7) <- global chunk (tid&7)^(row&7)
  const int sko = (((tid & 7) ^ (srow & 7)) << 3);
  const u16* Ag = A + (long)(bm + srow) * lda + kbase + sko;
  const u16* Bg = Bt + (long)(bn + srow) * ldb + kbase + sko;
  const long astep = 32L * lda;
  const long bstep = 32L * ldb;

#define STAGE_(bufI, kOff)                                                   \
  {                                                                          \
    _Pragma("unroll") for (int i_ = 0; i_ < 4; ++i_)                         \
      gload16(Ag + i_ * astep + (kOff), &Als[bufI][tid * 8 + i_ * 2048]);    \
    _Pragma("unroll") for (int i_ = 0; i_ < NBS; ++i_)                       \
      gload16(Bg + i_ * bstep + (kOff), &Bls[bufI][tid * 8 + i_ * 2048]);    \
  }

#define COMPUTE_(bufI)                                                       \
  {                                                                          \
    _Pragma("unroll") for (int kc = 0; kc < 2; ++kc) {                       \
      const int kx = ((kc * 4 + fq) ^ frx) << 3;                             \
      short8 af[4], bv[NJ];                                                  \
      _Pragma("unroll") for (int i = 0; i < 4; ++i)                          \
          af[i] = *(const short8*)&Als[bufI][(wm + i * 16 + fr) * 64 + kx];  \
      _Pragma("unroll") for (int j = 0; j < NJ; ++j)                         \
          bv[j] = *(const short8*)&Bls[bufI][(wn + j * 16 + fr) * 64 + kx];  \
      _Pragma("unroll") for (int i = 0; i < 4; ++i)                          \
          _Pragma("unroll") for (int j = 0; j < NJ; ++j)                     \
              acc[i][j] = __builtin_amdgcn_mfma_f32_16x16x32_bf16(           \
                  af[i], bv[j], acc[i][j], 0, 0, 0);                         \
    }                                                                        \
  }

  const int nsteps = kpart >> 6;   // even at all call sites (8/16)
  STAGE_(0, 0);
  __syncthreads();
  for (int s = 0; s < nsteps - 2; s += 2) {
    STAGE_(1, (s + 1) * 64);
    COMPUTE_(0);
    __syncthreads();
    STAGE_(0, (s + 2) * 64);
    COMPUTE_(1);
    __syncthreads();
  }
  STAGE_(1, (nsteps - 1) * 64);
  COMPUTE_(0);
  __syncthreads();
  COMPUTE_(1);
#undef STAGE_
#undef COMPUTE_

  // C/D frag mapping: col = lane&15, row = (lane>>4)*4 + r
#pragma unroll
  for (int i = 0; i < 4; ++i) {
#pragma unroll
    for (int j = 0; j < NJ; ++j) {
      int gc = bn + wn + j * 16 + fr;
#pragma unroll
      for (int r = 0; r < 4; ++r) {
        int gr = bm + wm + i * 16 + fq * 4 + r;
        float v = acc[i][j][r];
        if constexpr (EPI == E_BF16) {
          ((u16*)Cv + (long)zb * sC)[(long)gr * ldc + gc] = f2bf(v);
        } else if constexpr (EPI == E_SCALEBF) {
          ((u16*)Cv + (long)zb * sC)[(long)gr * ldc + gc] = f2bf(v * SCALE_);
        } else if constexpr (EPI == E_F32) {
          ((float*)Cv + (long)zb * sC)[(long)gr * ldc + gc] = v;
        } else if constexpr (EPI == E_PART) {
          // plain store of normalized partial into slab ks (stride 2^21 floats)
          float* C = (float*)Cv + ((long)ks << 21) + (long)zb * sC;
          C[(long)gr * ldc + gc] = v * (1.0f / colsum[zb * 256 + gr]);
        } else if constexpr (EPI == E_RELU) {
          float h = v + bias[gc];
          ((u16*)Cv + (long)zb * sC)[(long)gr * ldc + gc] = f2bf(h > 0.f ? h : 0.f);
        } else {  // E_ADDB (non-atomic, KSPLIT==1 only)
          float* C = (float*)Cv + (long)zb * sC;
          C[(long)gr * ldc + gc] += v + bias[gc];
        }
      }
    }
  }
}

// ---------- fused logits GEMM + softmax(n) + colsum ----------
// BM=256 (all n slots), BNF-wide l-tile (template), K=1024. 4 waves in M.
// Single-buffered (verified structure), BNF=64: 512 blocks, 40 KB LDS.
// BNF=32 measured WORSE (r12: stage-throughput-bound). BNF=64 is the optimum.
template <int BNF>
__global__ __launch_bounds__(256) void fls(const u16* __restrict__ qk,
                                           const u16* __restrict__ xn,
                                           u16* __restrict__ attnbf,
                                           float* __restrict__ colsum) {
  __shared__ u16 Als[256 * 64];    // 32 KB, qk rows (n)
  __shared__ u16 Bls[BNF * 64];    // xn rows (l)
  __shared__ float sred[4][BNF];
  __shared__ float ssum[4][BNF];
  constexpr int NJ = BNF / 16;     // l-fragments per lane-col group
  constexpr int NBS = BNF / 32;    // B staging gloads
  const int tid = threadIdx.x;
  const int z = blockIdx.z;
  const int l0 = blockIdx.x * BNF;
  const u16* A = qk + (long)z * 262144;     // [256][1024]
  const u16* B = xn + (long)z * 4194304;    // [4096][1024]
  const int lane = tid & 63;
  const int w = tid >> 6;
  const int wm = w * 64;
  const int fr = lane & 15, fq = lane >> 4;
  const int frx = fr & 7;
  f32x4 acc[4][NJ] = {};

  const int srow = tid >> 3;
  const int sko = (((tid & 7) ^ (srow & 7)) << 3);
  const u16* Ag = A + (long)srow * 1024 + sko;
  const u16* Bg = B + (long)(l0 + srow) * 1024 + sko;
  u16* Al = Als + tid * 8;
  u16* Bl = Bls + tid * 8;

  for (int k0 = 0; k0 < 1024; k0 += 64) {
#pragma unroll
    for (int i = 0; i < 8; ++i)
      gload16(Ag + (long)i * 32768 + k0, Al + i * 2048);
#pragma unroll
    for (int i = 0; i < NBS; ++i)
      gload16(Bg + (long)i * 32768 + k0, Bl + i * 2048);
    __syncthreads();
#pragma unroll
    for (int kc = 0; kc < 2; ++kc) {
      const int kx = ((kc * 4 + fq) ^ frx) << 3;
      short8 af[4], bf[NJ];
#pragma unroll
      for (int i = 0; i < 4; ++i)
        af[i] = *(const short8*)&Als[(wm + i * 16 + fr) * 64 + kx];
#pragma unroll
      for (int j = 0; j < NJ; ++j)
        bf[j] = *(const short8*)&Bls[(j * 16 + fr) * 64 + kx];
#pragma unroll
      for (int i = 0; i < 4; ++i)
#pragma unroll
        for (int j = 0; j < NJ; ++j)
          acc[i][j] = __builtin_amdgcn_mfma_f32_16x16x32_bf16(af[i], bf[j], acc[i][j], 0, 0, 0);
    }
    __syncthreads();
  }

  // ---- softmax over n (256) per l-col; lane holds rows (i,r) of cols (j,fr)
  float mj[NJ];
#pragma unroll
  for (int j = 0; j < NJ; ++j) {
    float m = acc[0][j][0];
#pragma unroll
    for (int i = 0; i < 4; ++i)
#pragma unroll
      for (int r = 0; r < 4; ++r) m = fmaxf(m, acc[i][j][r]);
    m = fmaxf(m, __shfl_xor(m, 16));
    m = fmaxf(m, __shfl_xor(m, 32));
    mj[j] = m;
  }
  if (fq == 0) {
#pragma unroll
    for (int j = 0; j < NJ; ++j) sred[w][j * 16 + fr] = mj[j];
  }
  __syncthreads();
  float M4[NJ];
#pragma unroll
  for (int j = 0; j < NJ; ++j) {
    int c = j * 16 + fr;
    M4[j] = fmaxf(fmaxf(sred[0][c], sred[1][c]), fmaxf(sred[2][c], sred[3][c]));
  }
  float pj[NJ];
#pragma unroll
  for (int j = 0; j < NJ; ++j) pj[j] = 0.f;
#pragma unroll
  for (int i = 0; i < 4; ++i)
#pragma unroll
    for (int j = 0; j < NJ; ++j)
#pragma unroll
      for (int r = 0; r < 4; ++r) {
        float e = __expf(acc[i][j][r] - M4[j]);
        acc[i][j][r] = e;
        pj[j] += e;
      }
#pragma unroll
  for (int j = 0; j < NJ; ++j) {
    pj[j] += __shfl_xor(pj[j], 16);
    pj[j] += __shfl_xor(pj[j], 32);
  }
  if (fq == 0) {
#pragma unroll
    for (int j = 0; j < NJ; ++j) ssum[w][j * 16 + fr] = pj[j];
  }
  __syncthreads();
  float inv[NJ];
#pragma unroll
  for (int j = 0; j < NJ; ++j) {
    int c = j * 16 + fr;
    inv[j] = 1.0f / (ssum[0][c] + ssum[1][c] + ssum[2][c] + ssum[3][c]);
  }
  // ---- write bf16 attn + colsum partials
  u16* outp = attnbf + (long)z * 1048576;
#pragma unroll
  for (int i = 0; i < 4; ++i) {
#pragma unroll
    for (int r = 0; r < 4; ++r) {
      int n = wm + i * 16 + fq * 4 + r;
      float cs = 0.f;
#pragma unroll
      for (int j = 0; j < NJ; ++j) {
        float a = acc[i][j][r] * inv[j] + 1e-8f;
        u16 ab = f2bf(a);
        outp[(long)n * 4096 + l0 + j * 16 + fr] = ab;
        cs += bf2f(ab);
      }
      cs += __shfl_xor(cs, 1);
      cs += __shfl_xor(cs, 2);
      cs += __shfl_xor(cs, 4);
      cs += __shfl_xor(cs, 8);
      if (fr == 0) atomicAdd(&colsum[z * 256 + n], cs);
    }
  }
}

// ---------- row LN over D=1024, fp32 in -> bf16 out ----------
// part != null: xv = in + sum of 4 partial slabs (stride 2^21), write back to
// tupd (the updated templates), then LN.  cz != null: zero colsum.
__global__ __launch_bounds__(256) void row_ln_bf(const float* in,
                                                 float* tupd,
                                                 u16* __restrict__ out,
                                                 const float* __restrict__ g,
                                                 const float* __restrict__ bvec,
                                                 const float* part,
                                                 float* __restrict__ cz) {
  if (cz && blockIdx.x < 8) cz[blockIdx.x * 256 + threadIdx.x] = 0.f;
  long base = (long)blockIdx.x * 1024;
  int c = threadIdx.x << 2;
  float4 xv = *(const float4*)&in[base + c];
  if (part) {
    const float* p = part + base + c;
    float4 a0 = *(const float4*)(p);
    float4 a1 = *(const float4*)(p + 2097152);
    float4 a2 = *(const float4*)(p + 4194304);
    float4 a3 = *(const float4*)(p + 6291456);
    xv.x += a0.x + a1.x + a2.x + a3.x;
    xv.y += a0.y + a1.y + a2.y + a3.y;
    xv.z += a0.z + a1.z + a2.z + a3.z;
    xv.w += a0.w + a1.w + a2.w + a3.w;
    *(float4*)&tupd[base + c] = xv;
  }
  float s = xv.x + xv.y + xv.z + xv.w;
  float s2 = xv.x * xv.x + xv.y * xv.y + xv.z * xv.z + xv.w * xv.w;
#pragma unroll
  for (int off = 32; off > 0; off >>= 1) {
    s += __shfl_down(s, off);
    s2 += __shfl_down(s2, off);
  }
  __shared__ float sh[8];
  if ((threadIdx.x & 63) == 0) {
    sh[threadIdx.x >> 6] = s;
    sh[4 + (threadIdx.x >> 6)] = s2;
  }
  __syncthreads();
  float ts = sh[0] + sh[1] + sh[2] + sh[3];
  float t2 = sh[4] + sh[5] + sh[6] + sh[7];
  float mu = ts * (1.0f / 1024.0f);
  float rs = rsqrtf(t2 * (1.0f / 1024.0f) - mu * mu + EPS_);
  ushort4 o;
  o.x = f2bf((xv.x - mu) * rs * g[c + 0] + bvec[c + 0]);
  o.y = f2bf((xv.y - mu) * rs * g[c + 1] + bvec[c + 1]);
  o.z = f2bf((xv.z - mu) * rs * g[c + 2] + bvec[c + 2]);
  o.w = f2bf((xv.w - mu) * rs * g[c + 3] + bvec[c + 3]);
  *(ushort4*)&out[base + c] = o;
}

// ---------- fused finale: attn_final (blocks <8192) + templates transpose ----
__global__ __launch_bounds__(256) void finalize(const u16* __restrict__ ab,
                                                const float* __restrict__ cs,
                                                float* __restrict__ attnOut,
                                                const float* __restrict__ tmpl,
                                                float* __restrict__ outT) {
  __shared__ float tile[32][33];
  const int b = blockIdx.x;
  if (b < 8192) {
    long i4 = (long)b * 256 + threadIdx.x;   // ushort4 index
    ushort4 v = *(const ushort4*)&ab[i4 * 4];
    float c = cs[i4 >> 10];                  // (i4*4)>>12
    float4 o;
    o.x = bf2f(v.x) / c;
    o.y = bf2f(v.y) / c;
    o.z = bf2f(v.z) / c;
    o.w = bf2f(v.w) / c;
    *(float4*)&attnOut[i4 * 4] = o;
  } else {
    // transpose tmpl [z][256][1024] -> outT [z][1024][256]; was grid (32,8,8)
    int r = b - 8192;
    int z = r >> 8, by = (r >> 5) & 7, bx = r & 31;
    int rt = by * 32, ct = bx * 32;
    int tx = threadIdx.x & 31, ty = threadIdx.x >> 5;
    const float* s = tmpl + (long)z * 262144;
    float* d = outT + (long)z * 262144;
#pragma unroll
    for (int k = 0; k < 32; k += 8) tile[ty + k][tx] = s[(long)(rt + ty + k) * 1024 + ct + tx];
    __syncthreads();
#pragma unroll
    for (int k = 0; k < 32; k += 8) d[(long)(ct + ty + k) * 256 + rt + tx] = tile[tx][ty + k];
  }
}

extern "C" void kernel_launch(void* const* d_in, const int* in_sizes, int n_in,
                              void* d_out, int out_size, void* d_ws, size_t ws_size,
                              hipStream_t stream) {
  const float* x       = (const float*)d_in[0];
  const float* tinit   = (const float*)d_in[1];
  const float* Wq      = (const float*)d_in[2];
  const float* Wk      = (const float*)d_in[3];
  const float* Wv      = (const float*)d_in[4];
  const float* ln_in_g = (const float*)d_in[5];
  const float* ln_in_b = (const float*)d_in[6];
  const float* ln_t_g  = (const float*)d_in[7];
  const float* ln_t_b  = (const float*)d_in[8];
  const float* ln_m_g  = (const float*)d_in[9];
  const float* ln_m_b  = (const float*)d_in[10];
  const float* W1      = (const float*)d_in[11];
  const float* b1      = (const float*)d_in[12];
  const float* W2      = (const float*)d_in[13];
  const float* b2      = (const float*)d_in[14];
  (void)in_sizes; (void)n_in; (void)out_size; (void)ws_size;

  // ---- workspace (~202 MiB peak) ----
  char* ws = (char*)d_ws;
  size_t off = 0;
  auto alloc = [&](size_t bytes) {
    void* p = ws + off;
    off += (bytes + 255) & ~(size_t)255;
    return p;
  };
  float* meanp   = (float*)alloc(32768ULL * 4);
  float* rstdp   = (float*)alloc(32768ULL * 4);
  float* ps      = (float*)alloc(262144ULL * 4);    // 8x32768 partial sums
  float* ps2     = (float*)alloc(262144ULL * 4);
  u16* xn        = (u16*)alloc(33554432ULL * 2);    // [8,4096,1024] bf16, 64 MB
  u16* vT        = (u16*)alloc(33554432ULL * 2);    // [8,1024,4096] bf16, 64 MB
  u16* attnbf    = (u16*)alloc(8388608ULL * 2);     // [8*256,4096] bf16, 16 MB
  u16* tln       = (u16*)alloc(2097152ULL * 2);     // tln / mfeat (aliased)
  u16* qk        = (u16*)alloc(2097152ULL * 2);
  u16* hidden    = (u16*)alloc(1048576ULL * 2);
  float* tmpl    = (float*)alloc(2097152ULL * 4);   // [8*256,1024] fp32
  float* Pu      = (float*)alloc(4ULL * 2097152 * 4); // 4 partial slabs, 32 MB
  u16* WqkT      = (u16*)alloc(1048576ULL * 2);     // scale*Wk*Wq^T
  u16* WvT       = (u16*)alloc(1048576ULL * 2);
  u16* W1T       = (u16*)alloc(524288ULL * 2);
  u16* W2T       = (u16*)alloc(524288ULL * 2);
  float* colsum  = (float*)alloc(2048ULL * 4);

  // temp bf16 weight casts live in attnbf slab (dead until first fls)
  u16* Wkbf = attnbf;
  u16* Wqbf = attnbf + 1048576;

  float* outT        = (float*)d_out;               // [B,D,N] 8 MB
  float* attnOutBase = (float*)d_out + 2097152;     // [B,N,L] fp32 final

  dim3 blk(256);

  // fused setup: ln_part + weight casts, then ln_red + tmpl broadcast
  setup1<<<dim3(14336), blk, 0, stream>>>(x, ps, ps2, Wk, Wq, Wkbf, Wqbf,
                                          Wv, W1, W2, WvT, W1T, W2T);
  setup2<<<dim3(8192), blk, 0, stream>>>(ps, ps2, meanp, rstdp, tinit, tmpl);
  mgemm<E_SCALEBF><<<dim3(8, 8, 1), blk, 0, stream>>>(
      Wkbf, Wqbf, WqkT, 1024, 1024, 1024, 1024, 0, 0, 0, nullptr, nullptr);
  xn_make<<<dim3(128, 32, 8), blk, 0, stream>>>(x, xn, meanp, rstdp, ln_in_g, ln_in_b);
  // vT[z][d][l] = sum_c WvT[d][c] * xn[z][l][c]
  mgemm<E_BF16><<<dim3(32, 8, 8), blk, 0, stream>>>(
      WvT, xn, vT, 1024, 1024, 1024, 4096, 0, 4194304L, 4194304L, nullptr, nullptr);

  for (int it = 0; it < 6; ++it) {
    // t-LN (also zeros colsum for this iteration's fls)
    row_ln_bf<<<dim3(2048), blk, 0, stream>>>(tmpl, nullptr, tln, ln_t_g, ln_t_b,
                                              nullptr, colsum);
    // qk[row][c] = sum_dt tln[row][dt] * WqkT[c][dt]   (BN=64: 256 blocks)
    mgemm<E_BF16, 1, 64><<<dim3(16, 16, 1), blk, 0, stream>>>(
        tln, WqkT, qk, 1024, 1024, 1024, 1024, 0, 0, 0, nullptr, nullptr);
    // fused logits + softmax(n) + colsum -> attnbf bf16  (BNF=64: 512 blocks)
    fls<64><<<dim3(64, 1, 8), blk, 0, stream>>>(qk, xn, attnbf, colsum);
    // P[ks] = (partial_K sum_l attn[n][l]*vT[z][d][l]) / colsum  (split-K=4,
    // plain stores, no atomics)
    mgemm<E_PART, 4><<<dim3(8, 2, 32), blk, 0, stream>>>(
        attnbf, vT, Pu, 4096, 4096, 4096, 1024, 1048576L, 4194304L, 262144L,
        nullptr, colsum);
    // m-LN fused with tmpl += sum(P): writes updated tmpl and LN -> tln
    row_ln_bf<<<dim3(2048), blk, 0, stream>>>(tmpl, tmpl, tln, ln_m_g, ln_m_b,
                                              Pu, nullptr);
    // hidden = relu(mfeat @ W1 + b1)   (BN=64: 128 blocks)
    mgemm<E_RELU, 1, 64><<<dim3(8, 16, 1), blk, 0, stream>>>(
        tln, W1T, hidden, 1024, 1024, 1024, 512, 0, 0, 0, b1, nullptr);
    // tmpl += hidden @ W2 + b2   (BN=64: 256 blocks, non-atomic)
    mgemm<E_ADDB, 1, 64><<<dim3(16, 16, 1), blk, 0, stream>>>(
        hidden, W2T, tmpl, 512, 512, 512, 1024, 0, 0, 0, b2, nullptr);
  }

  // fused finale: attn normalize + templates transpose
  finalize<<<dim3(10240), blk, 0, stream>>>(attnbf, colsum, attnOutBase, tmpl, outT);
}